// Round 6
// baseline (10413.069 us; speedup 1.0000x reference)
//
#include <hip/hip_runtime.h>
#include <stdint.h>

// AttentionBlock: B=8, H*W=4096, C=512; f32 inputs (runtime-detected), f32 out.
// R6: output dtype fixed to f32 (R4/R5's absmax = sqrt(2)*max|ref| proved the
// validator reads f32). xn lives in d_out as f32; internal GEMM pipeline bf16;
// naive vector GEMM retained as the correctness anchor.

#define BDIM 8
#define SDIM 4096      // H*W
#define CDIM 512
#define SC   2097152   // SDIM*CDIM per-batch elements

typedef unsigned short u16;

__device__ __forceinline__ float b2f(u16 h) {
  union { float f; uint32_t u; } z; z.u = ((uint32_t)h) << 16; return z.f;
}
__device__ __forceinline__ u16 f2b(float f) {
  union { float f; uint32_t u; } z; z.f = f;
  uint32_t u = z.u;
  return (u16)((u + 0x7fffu + ((u >> 16) & 1u)) >> 16);  // RNE
}
__device__ __forceinline__ float sanitize(float v) {
  return fminf(fmaxf(v, -1e4f), 1e4f);
}

// ---------------- input dtype probe (f32 vs bf16) ----------------
__global__ void detect_k(const u16* __restrict__ x, int* __restrict__ flag) {
  int lane = threadIdx.x;                      // 64 lanes
  float v = fabsf(b2f(x[lane * 2]));
  bool huge = !(v < 1e4f);                     // true for NaN too
  unsigned long long m = __ballot(huge);
  if (lane == 0) *flag = (m != 0ull) ? 1 : 0;
}

// ---------------- instance norm ----------------
__global__ void norm_partial(const void* __restrict__ xv, const int* __restrict__ flag,
                             float* __restrict__ sums, float* __restrict__ sumsq) {
  bool isf32 = *flag != 0;
  int c = blockIdx.x * 256 + threadIdx.x;     // 512 channels
  int b = blockIdx.y;                          // 8
  int s0 = blockIdx.z * 256;                   // 16 spatial chunks
  size_t base = (size_t)b * SDIM * CDIM + c;
  float s = 0.f, s2 = 0.f;
  if (isf32) {
    const float* p = (const float*)xv + base;
    #pragma unroll 4
    for (int i = 0; i < 256; ++i) {
      float v = p[(size_t)(s0 + i) * CDIM];
      s += v; s2 += v * v;
    }
  } else {
    const u16* p = (const u16*)xv + base;
    #pragma unroll 4
    for (int i = 0; i < 256; ++i) {
      float v = b2f(p[(size_t)(s0 + i) * CDIM]);
      s += v; s2 += v * v;
    }
  }
  atomicAdd(&sums[b * CDIM + c], s);
  atomicAdd(&sumsq[b * CDIM + c], s2);
}

__global__ void norm_finalize(const float* __restrict__ sums, const float* __restrict__ sumsq,
                              const void* __restrict__ gamma, const void* __restrict__ beta,
                              const int* __restrict__ flag,
                              float* __restrict__ scale, float* __restrict__ shift) {
  bool isf32 = *flag != 0;
  int i = blockIdx.x * 256 + threadIdx.x;      // 4096 = B*C
  int c = i & (CDIM - 1);
  float mean = sums[i] * (1.f / SDIM);
  float var  = sumsq[i] * (1.f / SDIM) - mean * mean;
  float gv = isf32 ? ((const float*)gamma)[c] : b2f(((const u16*)gamma)[c]);
  float bv = isf32 ? ((const float*)beta)[c]  : b2f(((const u16*)beta)[c]);
  float g = gv * rsqrtf(var + 1e-3f);
  scale[i] = g;
  shift[i] = bv - mean * g;
}

// writes f32 xn into d_out (8 elems/thread)
__global__ void normalize_k(const void* __restrict__ xv, const int* __restrict__ flag,
                            const float* __restrict__ scale, const float* __restrict__ shift,
                            float* __restrict__ xn) {
  bool isf32 = *flag != 0;
  int i = blockIdx.x * 256 + threadIdx.x;      // one thread per 8 elements
  int c8 = (i & 63) * 8;
  int b  = i >> 18;
  float in[8];
  if (isf32) {
    float4 f0 = ((const float4*)xv)[(size_t)i * 2];
    float4 f1 = ((const float4*)xv)[(size_t)i * 2 + 1];
    in[0]=f0.x; in[1]=f0.y; in[2]=f0.z; in[3]=f0.w;
    in[4]=f1.x; in[5]=f1.y; in[6]=f1.z; in[7]=f1.w;
  } else {
    uint4 u = ((const uint4*)xv)[i];
    u16* pu = (u16*)&u;
    #pragma unroll
    for (int j = 0; j < 8; ++j) in[j] = b2f(pu[j]);
  }
  const float4* s4 = (const float4*)(scale + b * CDIM + c8);
  const float4* h4 = (const float4*)(shift + b * CDIM + c8);
  float4 sA = s4[0], sB = s4[1], hA = h4[0], hB = h4[1];
  float sc[8] = {sA.x,sA.y,sA.z,sA.w,sB.x,sB.y,sB.z,sB.w};
  float sh[8] = {hA.x,hA.y,hA.z,hA.w,hB.x,hB.y,hB.z,hB.w};
  float4 o0, o1;
  o0.x = in[0]*sc[0]+sh[0]; o0.y = in[1]*sc[1]+sh[1];
  o0.z = in[2]*sc[2]+sh[2]; o0.w = in[3]*sc[3]+sh[3];
  o1.x = in[4]*sc[4]+sh[4]; o1.y = in[5]*sc[5]+sh[5];
  o1.z = in[6]*sc[6]+sh[6]; o1.w = in[7]*sc[7]+sh[7];
  ((float4*)xn)[(size_t)i * 2]     = o0;
  ((float4*)xn)[(size_t)i * 2 + 1] = o1;
}

// ---------------- bias prep (dual dtype) ----------------
__global__ void prep_bias_k(const void* __restrict__ bq, const void* __restrict__ bk,
                            const void* __restrict__ bv, const void* __restrict__ bp,
                            const int* __restrict__ flag,
                            u16* __restrict__ bqkv, u16* __restrict__ bpc) {
  bool isf32 = *flag != 0;
  int i = blockIdx.x * 256 + threadIdx.x;      // 2048
  const void* src; int j; u16* dst; int di;
  if (i < 512)       { src = bq; j = i;        dst = bqkv; di = i; }
  else if (i < 1024) { src = bk; j = i - 512;  dst = bqkv; di = i; }
  else if (i < 1536) { src = bv; j = i - 1024; dst = bqkv; di = i; }
  else               { src = bp; j = i - 1536; dst = bpc;  di = j; }
  dst[di] = isf32 ? f2b(((const float*)src)[j]) : ((const u16*)src)[j];
}

// ---------------- weight transpose 512x512 (input dtype -> bf16) ----------------
__global__ void wtrans_k(const void* __restrict__ src, u16* __restrict__ dst,
                         const int* __restrict__ flag) {
  bool isf32 = *flag != 0;
  __shared__ u16 t[32][33];
  int c0 = blockIdx.x * 32, r0 = blockIdx.y * 32;
  int tx = threadIdx.x & 31, ty = threadIdx.x >> 5;   // 32 x 8
  #pragma unroll
  for (int j = 0; j < 32; j += 8) {
    size_t si = (size_t)(r0 + ty + j) * 512 + c0 + tx;
    t[ty + j][tx] = isf32 ? f2b(((const float*)src)[si]) : ((const u16*)src)[si];
  }
  __syncthreads();
  #pragma unroll
  for (int j = 0; j < 32; j += 8)
    dst[(size_t)(c0 + ty + j) * 512 + r0 + tx] = t[tx][ty + j];
}

// ---------------- bf16 transpose (internal) ----------------
__global__ void transpose_k(const u16* __restrict__ src, u16* __restrict__ dst,
                            int R, int Cc, int ldS, int ldD) {
  __shared__ u16 t[32][33];
  int c0 = blockIdx.x * 32, r0 = blockIdx.y * 32;
  int tx = threadIdx.x & 31, ty = threadIdx.x >> 5;   // 32 x 8
  #pragma unroll
  for (int j = 0; j < 32; j += 8)
    t[ty + j][tx] = src[(size_t)(r0 + ty + j) * ldS + c0 + tx];
  __syncthreads();
  #pragma unroll
  for (int j = 0; j < 32; j += 8)
    dst[(size_t)(c0 + ty + j) * ldD + r0 + tx] = t[tx][ty + j];
}

// ---------------- softmax row stats + exp normalize (rows of 4096) ----------------
__global__ void rowstats_k(const u16* __restrict__ S, float* __restrict__ rowm,
                           float* __restrict__ rowl) {
  int row = blockIdx.x;
  int tid = threadIdx.x, lane = tid & 63, wave = tid >> 6;
  const uint4* p = (const uint4*)(S + (size_t)row * SDIM);
  uint4 a = p[tid], b = p[256 + tid];          // 16 bf16 per thread
  u16* pa = (u16*)&a; u16* pb = (u16*)&b;
  float v[16];
  #pragma unroll
  for (int j = 0; j < 8; ++j) { v[j] = sanitize(b2f(pa[j])); v[8 + j] = sanitize(b2f(pb[j])); }
  float m = v[0];
  #pragma unroll
  for (int j = 1; j < 16; ++j) m = fmaxf(m, v[j]);
  for (int o = 32; o; o >>= 1) m = fmaxf(m, __shfl_xor(m, o));
  __shared__ float red[8];
  if (lane == 0) red[wave] = m;
  __syncthreads();
  m = fmaxf(fmaxf(red[0], red[1]), fmaxf(red[2], red[3]));
  float l = 0.f;
  #pragma unroll
  for (int j = 0; j < 16; ++j) l += __expf(v[j] - m);
  for (int o = 32; o; o >>= 1) l += __shfl_xor(l, o);
  if (lane == 0) red[4 + wave] = l;
  __syncthreads();
  if (tid == 0) {
    rowm[row] = m;
    rowl[row] = 1.f / (red[4] + red[5] + red[6] + red[7]);
  }
}

__global__ void expnorm_k(u16* __restrict__ S, const float* __restrict__ rowm,
                          const float* __restrict__ rowl) {
  int i = blockIdx.x * 256 + threadIdx.x;      // 8 elems/thread, 512 threads/row
  int row = i >> 9;
  float m = rowm[row], il = rowl[row];
  uint4 u = ((uint4*)S)[i];
  u16* pu = (u16*)&u;
  union { u16 o[8]; uint4 v; } r;
  #pragma unroll
  for (int j = 0; j < 8; ++j) r.o[j] = f2b(__expf(sanitize(b2f(pu[j])) - m) * il);
  ((uint4*)S)[i] = r.v;
}

// ---------------- NAIVE GEMM: C[m][n] = alpha*sum_k A[m][k]*Bt[n][k] (+bias)(+resid) ----
// 64x64 tile, 256 threads (16x16), 4x4 outputs/thread, K-step 16, f32 LDS.
// a_f32: A operand is f32. io_f32: resid and C are f32. Branches wave-uniform.
__global__ __launch_bounds__(256) void gemm_naive(
    const void* __restrict__ A, int lda, int a_f32,
    const u16* __restrict__ Bt, int ldb,
    const u16* __restrict__ bias,
    const void* __restrict__ resid, void* __restrict__ C, int io_f32, int ldc,
    int M, int N, int K, float alpha)
{
  __shared__ float lsA[64][17];
  __shared__ float lsB[64][17];
  const int tid = threadIdx.x;
  const int tx = tid & 15, ty = tid >> 4;
  const int tileM = blockIdx.y * 64, tileN = blockIdx.x * 64;

  float acc[4][4] = {};

  for (int k0 = 0; k0 < K; k0 += 16) {
    #pragma unroll
    for (int e = 0; e < 4; ++e) {
      int idx = e * 256 + tid;                 // 0..1023
      int row = idx >> 4, kk = idx & 15;
      size_t ai = (size_t)(tileM + row) * lda + k0 + kk;
      lsA[row][kk] = a_f32 ? ((const float*)A)[ai] : b2f(((const u16*)A)[ai]);
      lsB[row][kk] = b2f(Bt[(size_t)(tileN + row) * ldb + k0 + kk]);
    }
    __syncthreads();
    #pragma unroll
    for (int kk = 0; kk < 16; ++kk) {
      float a[4], b[4];
      #pragma unroll
      for (int i = 0; i < 4; ++i) a[i] = lsA[ty * 4 + i][kk];
      #pragma unroll
      for (int j = 0; j < 4; ++j) b[j] = lsB[tx * 4 + j][kk];
      #pragma unroll
      for (int i = 0; i < 4; ++i)
        #pragma unroll
        for (int j = 0; j < 4; ++j)
          acc[i][j] += a[i] * b[j];
    }
    __syncthreads();
  }

  #pragma unroll
  for (int i = 0; i < 4; ++i) {
    int row = tileM + ty * 4 + i;
    #pragma unroll
    for (int j = 0; j < 4; ++j) {
      int col = tileN + tx * 4 + j;
      float v = acc[i][j] * alpha;
      if (bias) v += b2f(bias[col]);
      size_t idx = (size_t)row * ldc + col;
      if (io_f32) {
        if (resid) v += ((const float*)resid)[idx];
        ((float*)C)[idx] = v;
      } else {
        if (resid) v += b2f(((const u16*)resid)[idx]);
        ((u16*)C)[idx] = f2b(v);
      }
    }
  }
}

extern "C" void kernel_launch(void* const* d_in, const int* in_sizes, int n_in,
                              void* d_out, int out_size, void* d_ws, size_t ws_size,
                              hipStream_t stream) {
  const void* x     = d_in[0];
  const void* gamma = d_in[1];
  const void* beta  = d_in[2];
  const void* Wq = d_in[3]; const void* bq = d_in[4];
  const void* Wk = d_in[5]; const void* bk = d_in[6];
  const void* Wv = d_in[7]; const void* bv = d_in[8];
  const void* Wp = d_in[9]; const void* bp = d_in[10];
  float* out = (float*)d_out;                  // f32 output; also the xn buffer

  // ---- workspace layout (16B-aligned offsets) ----
  char* ws = (char*)d_ws;
  float* sums  = (float*)(ws);                 // 16 KB
  float* sumsq = (float*)(ws + 16384);         // 16 KB
  float* scale = (float*)(ws + 32768);         // 16 KB
  float* shift = (float*)(ws + 49152);         // 16 KB
  float* rowm  = (float*)(ws + 65536);         // 16 KB
  float* rowl  = (float*)(ws + 81920);         // 16 KB
  u16* bqkv    = (u16*)(ws + 98304);           // 3 KB
  u16* bpc     = (u16*)(ws + 102400);          // 1 KB
  int* flag    = (int*)(ws + 110592);          // 4 B
  u16* WqkvT   = (u16*)(ws + 114688);          // 1536x512 = 1.5 MB
  u16* WpT     = WqkvT + 786432;               // 512x512  = 0.5 MB
  u16* qkv     = WpT + 262144;                 // 4096x1536 = 12 MB; q-block doubles as attnV
  u16* vT      = qkv + 6291456;                // 512x4096 = 4 MB
  u16* Sb      = vT + 2097152;                 // RC x 4096 bf16
  const size_t S_off = 18989056;               // byte offset of Sb

  // largest score-chunk rows fitting ws (RC=4096 -> 50.1 MB; RC=128 -> 19.1 MB)
  int RC = 4096;
  while (RC > 128 && S_off + (size_t)RC * 8192 > ws_size) RC >>= 1;

  // 0) dtype probe
  detect_k<<<1, 64, 0, stream>>>((const u16*)x, flag);

  // 1) instance norm -> f32 xn lives in d_out
  hipMemsetAsync(sums, 0, 32768, stream);      // sums + sumsq
  norm_partial<<<dim3(2, 8, 16), 256, 0, stream>>>(x, flag, sums, sumsq);
  norm_finalize<<<16, 256, 0, stream>>>(sums, sumsq, gamma, beta, flag, scale, shift);
  normalize_k<<<8192, 256, 0, stream>>>(x, flag, scale, shift, out);

  // 2) weight/bias prep
  prep_bias_k<<<8, 256, 0, stream>>>(bq, bk, bv, bp, flag, bqkv, bpc);
  wtrans_k<<<dim3(16, 16), 256, 0, stream>>>(Wq, WqkvT,          flag);
  wtrans_k<<<dim3(16, 16), 256, 0, stream>>>(Wk, WqkvT + 262144, flag);
  wtrans_k<<<dim3(16, 16), 256, 0, stream>>>(Wv, WqkvT + 524288, flag);
  wtrans_k<<<dim3(16, 16), 256, 0, stream>>>(Wp, WpT,            flag);

  const float sscale = 0.0441941738241592f;    // 512^-0.5
  for (int b = 0; b < BDIM; ++b) {
    float* xnb = out + (size_t)b * SC;
    // fused QKV: (4096x512 f32) @ (512x1536 bf16) -> qkv bf16 (ldc=1536)
    gemm_naive<<<dim3(24, 64), 256, 0, stream>>>(xnb, 512, 1, WqkvT, 512, bqkv,
        nullptr, qkv, 0, 1536, 4096, 1536, 512, 1.f);
    // vT: v block (cols 1024..1535, ld 1536) -> 512 x 4096
    transpose_k<<<dim3(16, 128), 256, 0, stream>>>(qkv + 1024, vT, 4096, 512, 1536, 4096);
    for (int rc = 0; rc < SDIM; rc += RC) {
      // scores chunk: q rows rc.. @ k^T  (RC x 4096, K=512) -> Sb bf16
      gemm_naive<<<dim3(64, RC / 64), 256, 0, stream>>>(qkv + (size_t)rc * 1536, 1536, 0,
          qkv + 512, 1536, nullptr, nullptr, Sb, 0, 4096, RC, 4096, 512, sscale);
      rowstats_k<<<RC, 256, 0, stream>>>(Sb, rowm, rowl);
      expnorm_k<<<RC * 2, 256, 0, stream>>>(Sb, rowm, rowl);
      // attnV rows rc.. = P @ v  (RC x 512, K=4096) -> in-place into dead q rows
      gemm_naive<<<dim3(8, RC / 64), 256, 0, stream>>>(Sb, 4096, 0, vT, 4096, nullptr,
          nullptr, qkv + (size_t)rc * 1536, 0, 1536, RC, 512, 4096, 1.f);
    }
    // out_b = attnV @ Wp + bp + xn_b   (f32 resid/out, in-place)
    gemm_naive<<<dim3(8, 64), 256, 0, stream>>>(qkv, 1536, 0, WpT, 512, bpc,
        xnb, xnb, 1, 512, 4096, 512, 512, 1.f);
  }

  (void)in_sizes; (void)n_in; (void)out_size;
}

// Round 7
// 1585.878 us; speedup vs baseline: 6.5661x; 6.5661x over previous
//
#include <hip/hip_runtime.h>
#include <stdint.h>

// AttentionBlock: B=8, H*W=4096, C=512; f32 inputs, f32 out (both verified R6).
// R7: swap naive GEMM -> m97-style MFMA GEMM (128x128 tile, BK=64,
// global_load_lds staging; exonerated by R4==R5 bit-equality).
// Variants: A_F32 (QKV reads f32 xn), IO_F32 (final reads/writes f32 d_out).

#define BDIM 8
#define SDIM 4096      // H*W
#define CDIM 512
#define SC   2097152   // SDIM*CDIM per-batch elements

typedef unsigned short u16;
typedef __bf16 bf16x8 __attribute__((ext_vector_type(8)));
typedef float  f32x4  __attribute__((ext_vector_type(4)));

__device__ __forceinline__ float b2f(u16 h) {
  union { float f; uint32_t u; } z; z.u = ((uint32_t)h) << 16; return z.f;
}
__device__ __forceinline__ u16 f2b(float f) {
  union { float f; uint32_t u; } z; z.f = f;
  uint32_t u = z.u;
  return (u16)((u + 0x7fffu + ((u >> 16) & 1u)) >> 16);  // RNE
}
__device__ __forceinline__ float sanitize(float v) {
  return fminf(fmaxf(v, -1e4f), 1e4f);
}

// async global->LDS, 16B/lane; LDS dest = wave-uniform base + lane*16
__device__ __forceinline__ void gld_lds16(const u16* g, u16* l) {
  __builtin_amdgcn_global_load_lds(
      (__attribute__((address_space(1))) void*)(uintptr_t)(g),
      (__attribute__((address_space(3))) void*)(uint32_t)(uintptr_t)(l),
      16, 0, 0);
}

// ---------------- input dtype probe (f32 vs bf16) ----------------
__global__ void detect_k(const u16* __restrict__ x, int* __restrict__ flag) {
  int lane = threadIdx.x;                      // 64 lanes
  float v = fabsf(b2f(x[lane * 2]));
  bool huge = !(v < 1e4f);                     // true for NaN too
  unsigned long long m = __ballot(huge);
  if (lane == 0) *flag = (m != 0ull) ? 1 : 0;
}

// ---------------- instance norm ----------------
__global__ void norm_partial(const void* __restrict__ xv, const int* __restrict__ flag,
                             float* __restrict__ sums, float* __restrict__ sumsq) {
  bool isf32 = *flag != 0;
  int c = blockIdx.x * 256 + threadIdx.x;     // 512 channels
  int b = blockIdx.y;                          // 8
  int s0 = blockIdx.z * 256;                   // 16 spatial chunks
  size_t base = (size_t)b * SDIM * CDIM + c;
  float s = 0.f, s2 = 0.f;
  if (isf32) {
    const float* p = (const float*)xv + base;
    #pragma unroll 4
    for (int i = 0; i < 256; ++i) {
      float v = p[(size_t)(s0 + i) * CDIM];
      s += v; s2 += v * v;
    }
  } else {
    const u16* p = (const u16*)xv + base;
    #pragma unroll 4
    for (int i = 0; i < 256; ++i) {
      float v = b2f(p[(size_t)(s0 + i) * CDIM]);
      s += v; s2 += v * v;
    }
  }
  atomicAdd(&sums[b * CDIM + c], s);
  atomicAdd(&sumsq[b * CDIM + c], s2);
}

__global__ void norm_finalize(const float* __restrict__ sums, const float* __restrict__ sumsq,
                              const void* __restrict__ gamma, const void* __restrict__ beta,
                              const int* __restrict__ flag,
                              float* __restrict__ scale, float* __restrict__ shift) {
  bool isf32 = *flag != 0;
  int i = blockIdx.x * 256 + threadIdx.x;      // 4096 = B*C
  int c = i & (CDIM - 1);
  float mean = sums[i] * (1.f / SDIM);
  float var  = sumsq[i] * (1.f / SDIM) - mean * mean;
  float gv = isf32 ? ((const float*)gamma)[c] : b2f(((const u16*)gamma)[c]);
  float bv = isf32 ? ((const float*)beta)[c]  : b2f(((const u16*)beta)[c]);
  float g = gv * rsqrtf(var + 1e-3f);
  scale[i] = g;
  shift[i] = bv - mean * g;
}

// writes f32 xn into d_out (8 elems/thread)
__global__ void normalize_k(const void* __restrict__ xv, const int* __restrict__ flag,
                            const float* __restrict__ scale, const float* __restrict__ shift,
                            float* __restrict__ xn) {
  bool isf32 = *flag != 0;
  int i = blockIdx.x * 256 + threadIdx.x;      // one thread per 8 elements
  int c8 = (i & 63) * 8;
  int b  = i >> 18;
  float in[8];
  if (isf32) {
    float4 f0 = ((const float4*)xv)[(size_t)i * 2];
    float4 f1 = ((const float4*)xv)[(size_t)i * 2 + 1];
    in[0]=f0.x; in[1]=f0.y; in[2]=f0.z; in[3]=f0.w;
    in[4]=f1.x; in[5]=f1.y; in[6]=f1.z; in[7]=f1.w;
  } else {
    uint4 u = ((const uint4*)xv)[i];
    u16* pu = (u16*)&u;
    #pragma unroll
    for (int j = 0; j < 8; ++j) in[j] = b2f(pu[j]);
  }
  const float4* s4 = (const float4*)(scale + b * CDIM + c8);
  const float4* h4 = (const float4*)(shift + b * CDIM + c8);
  float4 sA = s4[0], sB = s4[1], hA = h4[0], hB = h4[1];
  float sc[8] = {sA.x,sA.y,sA.z,sA.w,sB.x,sB.y,sB.z,sB.w};
  float sh[8] = {hA.x,hA.y,hA.z,hA.w,hB.x,hB.y,hB.z,hB.w};
  float4 o0, o1;
  o0.x = in[0]*sc[0]+sh[0]; o0.y = in[1]*sc[1]+sh[1];
  o0.z = in[2]*sc[2]+sh[2]; o0.w = in[3]*sc[3]+sh[3];
  o1.x = in[4]*sc[4]+sh[4]; o1.y = in[5]*sc[5]+sh[5];
  o1.z = in[6]*sc[6]+sh[6]; o1.w = in[7]*sc[7]+sh[7];
  ((float4*)xn)[(size_t)i * 2]     = o0;
  ((float4*)xn)[(size_t)i * 2 + 1] = o1;
}

// ---------------- bias prep (dual dtype) ----------------
__global__ void prep_bias_k(const void* __restrict__ bq, const void* __restrict__ bk,
                            const void* __restrict__ bv, const void* __restrict__ bp,
                            const int* __restrict__ flag,
                            u16* __restrict__ bqkv, u16* __restrict__ bpc) {
  bool isf32 = *flag != 0;
  int i = blockIdx.x * 256 + threadIdx.x;      // 2048
  const void* src; int j; u16* dst; int di;
  if (i < 512)       { src = bq; j = i;        dst = bqkv; di = i; }
  else if (i < 1024) { src = bk; j = i - 512;  dst = bqkv; di = i; }
  else if (i < 1536) { src = bv; j = i - 1024; dst = bqkv; di = i; }
  else               { src = bp; j = i - 1536; dst = bpc;  di = j; }
  dst[di] = isf32 ? f2b(((const float*)src)[j]) : ((const u16*)src)[j];
}

// ---------------- weight transpose 512x512 (input dtype -> bf16) ----------------
__global__ void wtrans_k(const void* __restrict__ src, u16* __restrict__ dst,
                         const int* __restrict__ flag) {
  bool isf32 = *flag != 0;
  __shared__ u16 t[32][33];
  int c0 = blockIdx.x * 32, r0 = blockIdx.y * 32;
  int tx = threadIdx.x & 31, ty = threadIdx.x >> 5;   // 32 x 8
  #pragma unroll
  for (int j = 0; j < 32; j += 8) {
    size_t si = (size_t)(r0 + ty + j) * 512 + c0 + tx;
    t[ty + j][tx] = isf32 ? f2b(((const float*)src)[si]) : ((const u16*)src)[si];
  }
  __syncthreads();
  #pragma unroll
  for (int j = 0; j < 32; j += 8)
    dst[(size_t)(c0 + ty + j) * 512 + r0 + tx] = t[tx][ty + j];
}

// ---------------- bf16 transpose (internal) ----------------
__global__ void transpose_k(const u16* __restrict__ src, u16* __restrict__ dst,
                            int R, int Cc, int ldS, int ldD) {
  __shared__ u16 t[32][33];
  int c0 = blockIdx.x * 32, r0 = blockIdx.y * 32;
  int tx = threadIdx.x & 31, ty = threadIdx.x >> 5;   // 32 x 8
  #pragma unroll
  for (int j = 0; j < 32; j += 8)
    t[ty + j][tx] = src[(size_t)(r0 + ty + j) * ldS + c0 + tx];
  __syncthreads();
  #pragma unroll
  for (int j = 0; j < 32; j += 8)
    dst[(size_t)(c0 + ty + j) * ldD + r0 + tx] = t[tx][ty + j];
}

// ---------------- softmax row stats + exp normalize (rows of 4096) ----------------
__global__ void rowstats_k(const u16* __restrict__ S, float* __restrict__ rowm,
                           float* __restrict__ rowl) {
  int row = blockIdx.x;
  int tid = threadIdx.x, lane = tid & 63, wave = tid >> 6;
  const uint4* p = (const uint4*)(S + (size_t)row * SDIM);
  uint4 a = p[tid], b = p[256 + tid];          // 16 bf16 per thread
  u16* pa = (u16*)&a; u16* pb = (u16*)&b;
  float v[16];
  #pragma unroll
  for (int j = 0; j < 8; ++j) { v[j] = sanitize(b2f(pa[j])); v[8 + j] = sanitize(b2f(pb[j])); }
  float m = v[0];
  #pragma unroll
  for (int j = 1; j < 16; ++j) m = fmaxf(m, v[j]);
  for (int o = 32; o; o >>= 1) m = fmaxf(m, __shfl_xor(m, o));
  __shared__ float red[8];
  if (lane == 0) red[wave] = m;
  __syncthreads();
  m = fmaxf(fmaxf(red[0], red[1]), fmaxf(red[2], red[3]));
  float l = 0.f;
  #pragma unroll
  for (int j = 0; j < 16; ++j) l += __expf(v[j] - m);
  for (int o = 32; o; o >>= 1) l += __shfl_xor(l, o);
  if (lane == 0) red[4 + wave] = l;
  __syncthreads();
  if (tid == 0) {
    rowm[row] = m;
    rowl[row] = 1.f / (red[4] + red[5] + red[6] + red[7]);
  }
}

__global__ void expnorm_k(u16* __restrict__ S, const float* __restrict__ rowm,
                          const float* __restrict__ rowl) {
  int i = blockIdx.x * 256 + threadIdx.x;      // 8 elems/thread, 512 threads/row
  int row = i >> 9;
  float m = rowm[row], il = rowl[row];
  uint4 u = ((uint4*)S)[i];
  u16* pu = (u16*)&u;
  union { u16 o[8]; uint4 v; } r;
  #pragma unroll
  for (int j = 0; j < 8; ++j) r.o[j] = f2b(__expf(sanitize(b2f(pu[j])) - m) * il);
  ((uint4*)S)[i] = r.v;
}

// ---------------- MFMA GEMM: C[m][n] = alpha*sum_k A[m][k]*Bt[n][k] (+bias)(+resid)
// 128x128 tile, BK=64, 4 waves (2x2), wave 64x64 via 4x4 of 16x16x32 MFMA.
// B staged via global_load_lds (bf16). A: A_F32 ? f32->bf16 VGPR staging
// : global_load_lds. IO_F32: resid/C are f32. LDS 16B-chunk XOR swizzle.
template <int A_F32, int IO_F32>
__global__ __launch_bounds__(256) void gemm_bt(
    const void* __restrict__ A, int lda, const u16* __restrict__ Bt, int ldb,
    const u16* __restrict__ bias, const void* __restrict__ resid,
    void* __restrict__ C, int ldc, int M, int N, int K, float alpha)
{
  const int tid = threadIdx.x;
  const int lane = tid & 63;
  const int wave = tid >> 6;
  const int wm = wave & 1, wn = wave >> 1;
  const int tileM = blockIdx.y * 128, tileN = blockIdx.x * 128;
  const int quad = lane >> 4, l16 = lane & 15;

  __shared__ __align__(16) u16 lsA[128 * 64];
  __shared__ __align__(16) u16 lsB[128 * 64];

  f32x4 acc[4][4] = {};

  // transfer t = j*256 + tid -> linear LDS 16B slot t; global chunk XOR-swizzled
  int arow[4], agq[4];
  #pragma unroll
  for (int j = 0; j < 4; ++j) {
    int t = j * 256 + tid;
    arow[j] = t >> 3;
    agq[j]  = (t & 7) ^ (arow[j] & 7);
  }

  for (int k0 = 0; k0 < K; k0 += 64) {
    if (A_F32) {
      float4 fa[4][2];
      #pragma unroll
      for (int j = 0; j < 4; ++j) {
        const float* src = (const float*)A + (size_t)(tileM + arow[j]) * lda + k0 + agq[j] * 8;
        fa[j][0] = ((const float4*)src)[0];
        fa[j][1] = ((const float4*)src)[1];
      }
      #pragma unroll
      for (int j = 0; j < 4; ++j) {
        int t = j * 256 + tid;
        union { u16 o[8]; uint4 v; } r;
        r.o[0] = f2b(fa[j][0].x); r.o[1] = f2b(fa[j][0].y);
        r.o[2] = f2b(fa[j][0].z); r.o[3] = f2b(fa[j][0].w);
        r.o[4] = f2b(fa[j][1].x); r.o[5] = f2b(fa[j][1].y);
        r.o[6] = f2b(fa[j][1].z); r.o[7] = f2b(fa[j][1].w);
        *(uint4*)&lsA[t * 8] = r.v;
      }
      #pragma unroll
      for (int j = 0; j < 4; ++j) {
        int lb = (j * 256 + wave * 64) * 8;  // wave-uniform LDS base (u16 elems)
        gld_lds16(Bt + (size_t)(tileN + arow[j]) * ldb + k0 + agq[j] * 8, lsB + lb);
      }
    } else {
      #pragma unroll
      for (int j = 0; j < 4; ++j) {
        int lb = (j * 256 + wave * 64) * 8;
        gld_lds16((const u16*)A + (size_t)(tileM + arow[j]) * lda + k0 + agq[j] * 8, lsA + lb);
        gld_lds16(Bt + (size_t)(tileN + arow[j]) * ldb + k0 + agq[j] * 8, lsB + lb);
      }
    }
    __syncthreads();
    #pragma unroll
    for (int kk8 = 0; kk8 < 8; kk8 += 4) {   // two K=32 MFMA steps
      bf16x8 af[4], bfr[4];
      #pragma unroll
      for (int mi = 0; mi < 4; ++mi) {
        int r = wm * 64 + mi * 16 + l16;
        int slot = (kk8 + quad) ^ (r & 7);
        af[mi] = *(const bf16x8*)&lsA[r * 64 + slot * 8];
      }
      #pragma unroll
      for (int ni = 0; ni < 4; ++ni) {
        int r = wn * 64 + ni * 16 + l16;
        int slot = (kk8 + quad) ^ (r & 7);
        bfr[ni] = *(const bf16x8*)&lsB[r * 64 + slot * 8];
      }
      #pragma unroll
      for (int mi = 0; mi < 4; ++mi)
        #pragma unroll
        for (int ni = 0; ni < 4; ++ni)
          acc[mi][ni] = __builtin_amdgcn_mfma_f32_16x16x32_bf16(af[mi], bfr[ni], acc[mi][ni], 0, 0, 0);
    }
    __syncthreads();
  }

  // epilogue: C/D layout col=lane&15, row=quad*4+reg  [m89]
  #pragma unroll
  for (int mi = 0; mi < 4; ++mi) {
    #pragma unroll
    for (int ni = 0; ni < 4; ++ni) {
      f32x4 a = acc[mi][ni];
      int row0 = tileM + wm * 64 + mi * 16 + quad * 4;
      int col  = tileN + wn * 64 + ni * 16 + l16;
      float bv = bias ? b2f(bias[col]) : 0.f;
      #pragma unroll
      for (int r = 0; r < 4; ++r) {
        size_t idx = (size_t)(row0 + r) * ldc + col;
        float v = a[r] * alpha + bv;
        if (IO_F32) {
          if (resid) v += ((const float*)resid)[idx];
          ((float*)C)[idx] = v;
        } else {
          if (resid) v += b2f(((const u16*)resid)[idx]);
          ((u16*)C)[idx] = f2b(v);
        }
      }
    }
  }
}

extern "C" void kernel_launch(void* const* d_in, const int* in_sizes, int n_in,
                              void* d_out, int out_size, void* d_ws, size_t ws_size,
                              hipStream_t stream) {
  const void* x     = d_in[0];
  const void* gamma = d_in[1];
  const void* beta  = d_in[2];
  const void* Wq = d_in[3]; const void* bq = d_in[4];
  const void* Wk = d_in[5]; const void* bk = d_in[6];
  const void* Wv = d_in[7]; const void* bv = d_in[8];
  const void* Wp = d_in[9]; const void* bp = d_in[10];
  float* out = (float*)d_out;                  // f32 output; also the xn buffer

  // ---- workspace layout (16B-aligned offsets) ----
  char* ws = (char*)d_ws;
  float* sums  = (float*)(ws);                 // 16 KB
  float* sumsq = (float*)(ws + 16384);         // 16 KB
  float* scale = (float*)(ws + 32768);         // 16 KB
  float* shift = (float*)(ws + 49152);         // 16 KB
  float* rowm  = (float*)(ws + 65536);         // 16 KB
  float* rowl  = (float*)(ws + 81920);         // 16 KB
  u16* bqkv    = (u16*)(ws + 98304);           // 3 KB
  u16* bpc     = (u16*)(ws + 102400);          // 1 KB
  int* flag    = (int*)(ws + 110592);          // 4 B
  u16* WqkvT   = (u16*)(ws + 114688);          // 1536x512 = 1.5 MB
  u16* WpT     = WqkvT + 786432;               // 512x512  = 0.5 MB
  u16* qkv     = WpT + 262144;                 // 4096x1536 = 12 MB; q-block doubles as attnV
  u16* vT      = qkv + 6291456;                // 512x4096 = 4 MB
  u16* Sb      = vT + 2097152;                 // RC x 4096 bf16
  const size_t S_off = 18989056;               // byte offset of Sb

  // largest score-chunk rows fitting ws (RC=4096 -> 50.1 MB; RC=128 -> 19.1 MB)
  int RC = 4096;
  while (RC > 128 && S_off + (size_t)RC * 8192 > ws_size) RC >>= 1;

  // 0) dtype probe
  detect_k<<<1, 64, 0, stream>>>((const u16*)x, flag);

  // 1) instance norm -> f32 xn lives in d_out
  hipMemsetAsync(sums, 0, 32768, stream);      // sums + sumsq
  norm_partial<<<dim3(2, 8, 16), 256, 0, stream>>>(x, flag, sums, sumsq);
  norm_finalize<<<16, 256, 0, stream>>>(sums, sumsq, gamma, beta, flag, scale, shift);
  normalize_k<<<8192, 256, 0, stream>>>(x, flag, scale, shift, out);

  // 2) weight/bias prep
  prep_bias_k<<<8, 256, 0, stream>>>(bq, bk, bv, bp, flag, bqkv, bpc);
  wtrans_k<<<dim3(16, 16), 256, 0, stream>>>(Wq, WqkvT,          flag);
  wtrans_k<<<dim3(16, 16), 256, 0, stream>>>(Wk, WqkvT + 262144, flag);
  wtrans_k<<<dim3(16, 16), 256, 0, stream>>>(Wv, WqkvT + 524288, flag);
  wtrans_k<<<dim3(16, 16), 256, 0, stream>>>(Wp, WpT,            flag);

  const float sscale = 0.0441941738241592f;    // 512^-0.5
  for (int b = 0; b < BDIM; ++b) {
    float* xnb = out + (size_t)b * SC;
    // fused QKV: (4096x512 f32) @ (512x1536 bf16) -> qkv bf16 (ldc=1536)
    gemm_bt<1, 0><<<dim3(12, 32), 256, 0, stream>>>(xnb, 512, WqkvT, 512, bqkv,
        nullptr, qkv, 1536, 4096, 1536, 512, 1.f);
    // vT: v block (cols 1024..1535, ld 1536) -> 512 x 4096
    transpose_k<<<dim3(16, 128), 256, 0, stream>>>(qkv + 1024, vT, 4096, 512, 1536, 4096);
    for (int rc = 0; rc < SDIM; rc += RC) {
      // scores chunk: q rows rc.. @ k^T  (RC x 4096, K=512) -> Sb bf16
      gemm_bt<0, 0><<<dim3(32, RC / 128), 256, 0, stream>>>(qkv + (size_t)rc * 1536, 1536,
          qkv + 512, 1536, nullptr, nullptr, Sb, 4096, RC, 4096, 512, sscale);
      rowstats_k<<<RC, 256, 0, stream>>>(Sb, rowm, rowl);
      expnorm_k<<<RC * 2, 256, 0, stream>>>(Sb, rowm, rowl);
      // attnV rows rc.. = P @ v  (RC x 512, K=4096) -> in-place into dead q rows
      gemm_bt<0, 0><<<dim3(4, RC / 128), 256, 0, stream>>>(Sb, 4096,
          vT, 4096, nullptr, nullptr, qkv + (size_t)rc * 1536, 1536, RC, 512, 4096, 1.f);
    }
    // out_b = attnV @ Wp + bp + xn_b   (f32 resid/out, in-place)
    gemm_bt<0, 1><<<dim3(4, 32), 256, 0, stream>>>(qkv, 1536, WpT, 512, bpc,
        xnb, xnb, 512, 4096, 512, 512, 1.f);
  }

  (void)in_sizes; (void)n_in; (void)out_size;
}